// Round 1
// baseline (159.411 us; speedup 1.0000x reference)
//
#include <hip/hip_runtime.h>

// AttnPainter: B=8, N=256, W=128, K=10.
// pred = 1 - alpha_raw; alpha_raw ~ U[0,1) so pred > 0 everywhere => top-K
// along N is exactly {N-1 .. N-K}, composited back-to-front = ascending n.
// Fast path verifies that assumption per-pixel on the K loaded values and
// falls back to a fully general two-pass scan (no register arrays => no
// scratch spill on the hot path) if it ever fails.

#define B_  8
#define N_  256
#define W_  128
#define K_  10
#define WW_ (W_ * W_)

__global__ __launch_bounds__(256) void attn_painter_kernel(
    const float* __restrict__ alpha,   // (B, N, W, W)
    const float* __restrict__ colors,  // (B, N, 3)
    float* __restrict__ out)           // (B, 3, W, W)
{
    const int t = blockIdx.x * blockDim.x + threadIdx.x;
    if (t >= B_ * WW_) return;
    const int b = t / WW_;          // block-uniform (WW_ / 256 = 64 blocks per b)
    const int p = t - b * WW_;

    const float* ap = alpha  + (size_t)b * N_ * WW_ + p;
    const float* cp = colors + (size_t)b * N_ * 3;

    // Load the K candidate alphas (independent addresses -> pipelined loads).
    float vals[K_];
#pragma unroll
    for (int i = 0; i < K_; ++i)
        vals[i] = ap[(size_t)(N_ - K_ + i) * WW_];

    bool fast = true;
#pragma unroll
    for (int i = 0; i < K_; ++i)
        fast &= (1.0f - vals[i] > 0.0f);

    float cr = 1.0f, cg = 1.0f, cb = 1.0f;

    if (fast) {
        // Top-K == {N-K .. N-1}; composite in ascending n (reference applies
        // stroke_topk[:, K-1] first, which is n = N-K).
#pragma unroll
        for (int i = 0; i < K_; ++i) {
            const int n  = N_ - K_ + i;
            const float a  = 1.0f - vals[i];
            const float om = 1.0f - a;
            cr = cr * om + a * cp[n * 3 + 0];
            cg = cg * om + a * cp[n * 3 + 1];
            cb = cb * om + a * cp[n * 3 + 2];
        }
    } else {
        // General path (unreachable with the harness's U[0,1) inputs):
        // pass 1 finds the K-th largest n with pred>0; pass 2 composites
        // those strokes in ascending n. Entries with pred<=0 contribute
        // identity (a==0 case of the reference's zero-draw fill).
        int cnt = 0, nmin = 0;
        for (int n = N_ - 1; n >= 0; --n) {
            if (1.0f - ap[(size_t)n * WW_] > 0.0f) {
                if (++cnt == K_) { nmin = n; break; }
            }
        }
        for (int n = nmin; n < N_; ++n) {
            const float a = 1.0f - ap[(size_t)n * WW_];
            if (a > 0.0f) {
                const float om = 1.0f - a;
                cr = cr * om + a * cp[n * 3 + 0];
                cg = cg * om + a * cp[n * 3 + 1];
                cb = cb * om + a * cp[n * 3 + 2];
            }
        }
    }

    out[((size_t)b * 3 + 0) * WW_ + p] = cr;
    out[((size_t)b * 3 + 1) * WW_ + p] = cg;
    out[((size_t)b * 3 + 2) * WW_ + p] = cb;
}

extern "C" void kernel_launch(void* const* d_in, const int* in_sizes, int n_in,
                              void* d_out, int out_size, void* d_ws, size_t ws_size,
                              hipStream_t stream) {
    const float* alpha  = (const float*)d_in[0];  // (B, N, W, W) fp32
    const float* colors = (const float*)d_in[1];  // (B, N, 3)   fp32
    float* out = (float*)d_out;                   // (B, 3, W, W) fp32

    const int total = B_ * WW_;                   // 131072 pixels
    attn_painter_kernel<<<(total + 255) / 256, 256, 0, stream>>>(alpha, colors, out);
}